// Round 20
// baseline (153.553 us; speedup 1.0000x reference)
//
#include <hip/hip_runtime.h>

// ---------------------------------------------------------------------------
// SelfAttention (dual cross-attention): B=4, S=1024, HID=1024, NH=16, DH=64
//   q1,k1,v1,q2,k2,v2 = x @ W*.T + b*   (bf16 MFMA, f32 accum)
//   out5 = attn(q1,k2,v2), out3 = attn(q2,k1,v1)
// ---------------------------------------------------------------------------

typedef __attribute__((ext_vector_type(8))) short bf16x8;
typedef __attribute__((ext_vector_type(4))) short bf16x4;
typedef __attribute__((ext_vector_type(4))) float f32x4;
typedef __attribute__((ext_vector_type(4))) short s16x4;

#define MFMA16(a, b, c) __builtin_amdgcn_mfma_f32_16x16x32_bf16(a, b, c, 0, 0, 0)
#define BARRIER() asm volatile("s_barrier" ::: "memory")
#define VMCNT0() asm volatile("s_waitcnt vmcnt(0)" ::: "memory")

__device__ __forceinline__ f32x4 mfma16k(bf16x4 a, bf16x4 b, f32x4 c) {
#if __has_builtin(__builtin_amdgcn_mfma_f32_16x16x16bf16_1k)
  return __builtin_amdgcn_mfma_f32_16x16x16bf16_1k(a, b, c, 0, 0, 0);
#elif __has_builtin(__builtin_amdgcn_mfma_f32_16x16x16_bf16)
  return __builtin_amdgcn_mfma_f32_16x16x16_bf16(a, b, c, 0, 0, 0);
#else
  asm volatile("v_mfma_f32_16x16x16_bf16 %0, %1, %2, %0"
               : "+v"(c) : "v"(a), "v"(b));
  return c;
#endif
}

__device__ __forceinline__ unsigned short f2bf(float f) {
  unsigned u = __float_as_uint(f);
  u = (u + 0x7fffu + ((u >> 16) & 1u)) >> 16;  // RNE
  return (unsigned short)u;
}

__device__ __forceinline__ unsigned cvt_pk_bf16(float lo, float hi) {
  unsigned r;
  asm("v_cvt_pk_bf16_f32 %0, %1, %2" : "=v"(r) : "v"(lo), "v"(hi));
  return r;
}

__device__ __forceinline__ void gll16(const void* g, void* l) {
  __builtin_amdgcn_global_load_lds(
      (const __attribute__((address_space(1))) unsigned int*)g,
      (__attribute__((address_space(3))) unsigned int*)l, 16, 0, 0);
}

// ---------------------------------------------------------------------------
// Kernel 1: f32 -> bf16 conversion of x (4M) and the 6 weight matrices
// (6x1M). Grid-stride over 2.62M float4 slots, 2048 blocks (G11).
// ---------------------------------------------------------------------------
__global__ __launch_bounds__(256) void convert_k(
    const float* __restrict__ x,
    const float* __restrict__ W0, const float* __restrict__ W1,
    const float* __restrict__ W2, const float* __restrict__ W3,
    const float* __restrict__ W4, const float* __restrict__ W5,
    short* __restrict__ xbf, short* __restrict__ wbf) {
  const int total = (10 << 20) >> 2;  // 2.62M vec4 slots
  for (int tid = blockIdx.x * 256 + threadIdx.x; tid < total;
       tid += 2048 * 256) {
    const int e = tid << 2;
    const float* src;
    short* dst;
    int off;
    if (e < (4 << 20)) {
      src = x; dst = xbf; off = e;
    } else {
      const int j = e - (4 << 20);
      const int wsel = j >> 20;
      off = j & ((1 << 20) - 1);
      src = (wsel == 0) ? W0 : (wsel == 1) ? W1 : (wsel == 2) ? W2
          : (wsel == 3) ? W3 : (wsel == 4) ? W4 : W5;
      dst = wbf + ((size_t)wsel << 20);
    }
    const float4 v = *(const float4*)(src + off);
    s16x4 o;
    o.x = (short)f2bf(v.x);
    o.y = (short)f2bf(v.y);
    o.z = (short)f2bf(v.z);
    o.w = (short)f2bf(v.w);
    *(s16x4*)(dst + off) = o;
  }
}

// ---------------------------------------------------------------------------
// Kernel 2: projection GEMM — round-19 version verbatim. 128x192 block,
// BK=64, 256 thr (4 waves 2Mx2N, wave-tile 64x96), 2 blocks/CU (80 KB LDS),
// ns-inner L2 mapping, V sub-half swizzle in epilogue.
// ---------------------------------------------------------------------------
__global__ __launch_bounds__(256, 2) void proj_t2(
    const short* __restrict__ Ag, const short* __restrict__ Wall,
    const float* __restrict__ bq, const float* __restrict__ bk,
    const float* __restrict__ bv, const float* __restrict__ bq2,
    const float* __restrict__ bk2, const float* __restrict__ bv2,
    short* __restrict__ qkv) {
  __shared__ __align__(16) short As[2][8192];   // 128 x 64
  __shared__ __align__(16) short Bs[2][12288];  // 192 x 64

  const int bid = blockIdx.x;             // 1024
  const int xcd = bid & 7, i = bid >> 3;  // 128 per XCD
  const int ns = i & 3, mb = i >> 2;      // ns inner: A-panel reused x4
  const int nbase = (xcd * 4 + ns) * 192;
  const int m0 = mb << 7;

  const int t = threadIdx.x, lane = t & 63, w = t >> 6;
  const int g = lane >> 4, lr = lane & 15;
  const int wr = w >> 1, wc = w & 1;      // 2M x 2N waves; wave C = 64x96

  f32x4 acc[4][6] = {};

  auto stage_a = [&](int T) {  // A 128 rows, 4 instr/thread
#pragma unroll
    for (int ld = 0; ld < 4; ++ld) {
      const int slot = (ld << 8) + t;
      const int rr = slot >> 3;
      const int gc = (slot & 7) ^ (rr & 7);
      gll16(Ag + (size_t)(m0 + rr) * 1024 + (T << 6) + (gc << 3),
            &As[T & 1][slot * 8]);
    }
  };
  auto stage_b = [&](int T) {  // B 192 rows, 6 instr/thread
#pragma unroll
    for (int ld = 0; ld < 6; ++ld) {
      const int slot = (ld << 8) + t;
      const int rr = slot >> 3;
      const int gc = (slot & 7) ^ (rr & 7);
      gll16(Wall + (size_t)(nbase + rr) * 1024 + (T << 6) + (gc << 3),
            &Bs[T & 1][slot * 8]);
    }
  };

  stage_a(0); stage_b(0);
  VMCNT0();
  BARRIER();

#define LOAD_A(KK, TB)                                                    \
  _Pragma("unroll") for (int mi = 0; mi < 4; ++mi) {                      \
    const int rA = wr * 64 + mi * 16 + lr;                                \
    af[mi] = *(const bf16x8*)                                             \
        &As[TB][rA * 64 + ((((KK) * 4 + g) ^ (rA & 7)) << 3)];            \
  }
#define LOAD_B(KK, TB)                                                    \
  _Pragma("unroll") for (int nj = 0; nj < 6; ++nj) {                      \
    const int rB = wc * 96 + nj * 16 + lr;                                \
    bf[nj] = *(const bf16x8*)                                             \
        &Bs[TB][rB * 64 + ((((KK) * 4 + g) ^ (rB & 7)) << 3)];            \
  }
#define MFMA_C()                                                          \
  __builtin_amdgcn_s_setprio(1);                                          \
  _Pragma("unroll") for (int mi = 0; mi < 4; ++mi)                        \
    _Pragma("unroll") for (int nj = 0; nj < 6; ++nj)                      \
      acc[mi][nj] = MFMA16(af[mi], bf[nj], acc[mi][nj]);                  \
  __builtin_amdgcn_s_setprio(0);

  for (int T = 0; T < 16; ++T) {
    const int C = T & 1;
    const bool DV = T < 15;
    bf16x8 af[4], bf[6];
    { // phase 1: kk0 (10 ds); dribble next tile's A (4 gll16)
      LOAD_A(0, C); LOAD_B(0, C);
      if (DV) stage_a(T + 1);
      BARRIER();
      MFMA_C();
      BARRIER();
    }
    { // phase 2: kk1 (10 ds); dribble next tile's B (6 gll16); certify
      LOAD_A(1, C); LOAD_B(1, C);
      if (DV) stage_b(T + 1);
      BARRIER();
      MFMA_C();
      VMCNT0();
      BARRIER();
    }
  }

#undef LOAD_A
#undef LOAD_B
#undef MFMA_C

  // ---- epilogue: bias + bf16 pack into attention layouts (per-column p) ----
#pragma unroll
  for (int nj = 0; nj < 6; ++nj) {
    const int nn = nbase + wc * 96 + nj * 16 + lr;
    const int p = nn >> 10, nl = nn & 1023;
    const float* bp = (p == 0) ? bq : (p == 1) ? bk : (p == 2) ? bv
                    : (p == 3) ? bq2 : (p == 4) ? bk2 : bv2;
    const float bb = bp[nl];
    const int h = nl >> 6, d = nl & 63;
    const int pt = (p == 0 || p == 3) ? 0 : (p == 1 || p == 4) ? 1 : 2;
    unsigned short* dst = (unsigned short*)qkv + ((size_t)p << 22);
#pragma unroll
    for (int mi = 0; mi < 4; ++mi) {
#pragma unroll
      for (int r = 0; r < 4; ++r) {
        const int m = m0 + wr * 64 + mi * 16 + (g << 2) + r;
        const int b = m >> 10, s = m & 1023;
        const unsigned short val = f2bf(acc[mi][nj][r] + bb);
        size_t idx;
        if (pt == 0) {
          idx = ((size_t)(((b << 4) + h) * 1024 + s) << 6) + d;
        } else if (pt == 1) {
          const int d2 = (d & 7) | (((d >> 3) ^ (s & 7)) << 3);
          idx = ((size_t)(((b << 4) + h) * 1024 + s) << 6) + d2;
        } else {
          const int tt = s >> 6, s2 = s & 63;
          const int w2 = (s2 & 7) ^ (((d >> 3) & 1) << 2);
          const int s3 = w2 | (((s2 >> 3) ^ (d & 7)) << 3);
          idx = ((size_t)((((b << 4) + h) * 16 + tt) * 64 + d) << 6) + s3;
        }
        dst[idx] = val;
      }
    }
  }
}

// ---------------------------------------------------------------------------
// Kernel 3: flash attention, swapped-QK^T in-register-P form. Round-20:
// 32 q-rows per wave (two streams A/B; Q-tile 256/block, grid 512). Each
// staged K-frag and V-frag feeds BOTH streams' MFMAs -> LDS reads, staging
// and barrier events per q-row halve; two softmax chains double VALU ILP.
// Streams sequenced (A softmax fully -> paA before B) to cap VGPR liveness.
// ---------------------------------------------------------------------------
__global__ __launch_bounds__(512) void attn_k(const short* __restrict__ qkv,
                                              float* __restrict__ out) {
  __shared__ __align__(16) short Ks[2][64 * 64];
  __shared__ __align__(16) short Vs[2][64 * 64];

  const int L = blockIdx.x;  // 512 blocks
  const int xcd = L & 7, ss = L >> 3;   // ss 0..63
  const int qt = ss & 3, pg = ss >> 2;  // 4 q-tiles of 256 rows
  const int pp = xcd + (pg << 3);       // 0..127
  const int hb = pp & 63, dir = pp >> 6;

  const short* Q = qkv + ((size_t)(dir ? 3 : 0) << 22) + ((size_t)hb << 16);
  const short* K = qkv + ((size_t)(dir ? 1 : 4) << 22) + ((size_t)hb << 16);
  const short* V = qkv + ((size_t)(dir ? 2 : 5) << 22) + ((size_t)hb << 16);
  float* O = out + ((size_t)dir << 22);

  const int t = threadIdx.x, lane = t & 63, w = t >> 6;  // w 0..7
  const int g = lane >> 4, lr = lane & 15;

  const int qrow = (qt << 8) + (w << 5) + lr;  // stream A; B = +16
  bf16x8 qfA[2], qfB[2];
  qfA[0] = *(const bf16x8*)(Q + qrow * 64 + g * 8);
  qfA[1] = *(const bf16x8*)(Q + qrow * 64 + 32 + g * 8);
  qfB[0] = *(const bf16x8*)(Q + (qrow + 16) * 64 + g * 8);
  qfB[1] = *(const bf16x8*)(Q + (qrow + 16) * 64 + 32 + g * 8);

  const bf16x4 ones4 = {0x3F80, 0x3F80, 0x3F80, 0x3F80};

  f32x4 oaccA[4] = {}, oaccB[4] = {};
  f32x4 laccA = {}, laccB = {};
  float mrunA = -3.0e38f, mrunB = -3.0e38f;
  const float CSC = 0.18033688f;       // (1/8) * log2(e)

  const int srow = t >> 3;             // staging row 0..63 (1 gll16/thread)
  const int scol = (t & 7) << 3;

  auto stage = [&](int kt, int buf) {
    gll16(K + (size_t)((kt << 6) + srow) * 64 + scol, &Ks[buf][w << 9]);
    gll16(V + (size_t)(kt << 12) + (size_t)srow * 64 + scol, &Vs[buf][w << 9]);
  };

  // softmax for one stream: sc (in), mrun/lacc/oacc (in-out), pa (out)
  auto softmax = [&](f32x4* sc, float& mrun, f32x4& lacc, f32x4* oacc,
                     bf16x4* pa) {
    float tm = fmaxf(fmaxf(fmaxf(sc[0][0], sc[0][1]),
                           fmaxf(sc[0][2], sc[0][3])),
                     fmaxf(fmaxf(sc[1][0], sc[1][1]),
                           fmaxf(sc[1][2], sc[1][3])));
    tm = fmaxf(tm, fmaxf(fmaxf(fmaxf(sc[2][0], sc[2][1]),
                               fmaxf(sc[2][2], sc[2][3])),
                         fmaxf(fmaxf(sc[3][0], sc[3][1]),
                               fmaxf(sc[3][2], sc[3][3]))));
    const bool ok = __all(fmaf(tm, CSC, -mrun) <= 8.0f);
    if (!ok) {
      float t2 = fmaxf(tm, __shfl_xor(tm, 16));
      t2 = fmaxf(t2, __shfl_xor(t2, 32));
      const float mnew = fmaxf(mrun, t2 * CSC);
      const float scq = exp2f(mrun - mnew);  // scale for q = lr of stream
      mrun = mnew;
#pragma unroll
      for (int r = 0; r < 4; ++r) {
        const float sr = __shfl(scq, (g << 2) + r);
        lacc[r] *= sr;
#pragma unroll
        for (int dn = 0; dn < 4; ++dn) oacc[dn][r] *= sr;
      }
    }
#pragma unroll
    for (int kn = 0; kn < 4; ++kn) {
      const float p0 = exp2f(fmaf(sc[kn][0], CSC, -mrun));
      const float p1 = exp2f(fmaf(sc[kn][1], CSC, -mrun));
      const float p2 = exp2f(fmaf(sc[kn][2], CSC, -mrun));
      const float p3 = exp2f(fmaf(sc[kn][3], CSC, -mrun));
      union { unsigned u[2]; bf16x4 v; } pk;
      pk.u[0] = cvt_pk_bf16(p0, p1);
      pk.u[1] = cvt_pk_bf16(p2, p3);
      pa[kn] = pk.v;
    }
  };

  // one KV tile with compile-time buffer index CUR
  auto tile = [&](int kt, auto curc) {
    constexpr int CUR = decltype(curc)::value;
    if (kt < 15) stage(kt + 1, CUR ^ 1);

    // ---- S^T = K Q^T, both streams off each K-frag ----
    f32x4 scA[4] = {}, scB[4] = {};
    __builtin_amdgcn_s_setprio(1);
#pragma unroll
    for (int dk = 0; dk < 2; ++dk) {
#pragma unroll
      for (int kn = 0; kn < 4; ++kn) {
        const int krow = kn * 16 + lr;
        const bf16x8 kf = *(const bf16x8*)
            &Ks[CUR][krow * 64 +
                     ((((dk << 6) + (g << 4)) ^ ((krow & 7) << 4)) >> 1)];
        scA[kn] = MFMA16(kf, qfA[dk], scA[kn]);
        scB[kn] = MFMA16(kf, qfB[dk], scB[kn]);
      }
    }
    __builtin_amdgcn_s_setprio(0);

    bf16x4 paA[4], paB[4];
    softmax(scA, mrunA, laccA, oaccA, paA);
    softmax(scB, mrunB, laccB, oaccB, paB);

    // ---- O += P V, both streams off each V-frag ----
    __builtin_amdgcn_s_setprio(1);
#pragma unroll
    for (int kn = 0; kn < 4; ++kn) {
      laccA = mfma16k(paA[kn], ones4, laccA);
      laccB = mfma16k(paB[kn], ones4, laccB);
#pragma unroll
      for (int dn = 0; dn < 4; ++dn) {
        const int vrow = dn * 16 + lr;
        const int ch = (2 * kn + (g >> 1)) ^ (vrow & 7);  // 16B-chunk swizzle
        const int sub = (((g & 1) ^ ((lr >> 3) & 1)) << 2);  // 8B sub-half
        const bf16x4 vf = *(const bf16x4*)
            &Vs[CUR][vrow * 64 + ch * 8 + sub];
        oaccA[dn] = mfma16k(paA[kn], vf, oaccA[dn]);
        oaccB[dn] = mfma16k(paB[kn], vf, oaccB[dn]);
      }
    }
    __builtin_amdgcn_s_setprio(0);

    VMCNT0();
    BARRIER();
  };

  stage(0, 0);
  VMCNT0();
  BARRIER();

#pragma unroll
  for (int kp = 0; kp < 8; ++kp) {
    tile(2 * kp, std::integral_constant<int, 0>{});
    tile(2 * kp + 1, std::integral_constant<int, 1>{});
  }

  // ---- epilogue: out[b][q][h*64+d] = oacc / l, both streams ----
  const int b = hb >> 4, h = hb & 15;
  float rlA[4], rlB[4];
#pragma unroll
  for (int r = 0; r < 4; ++r) {
    rlA[r] = 1.0f / laccA[r];
    rlB[r] = 1.0f / laccB[r];
  }
#pragma unroll
  for (int dn = 0; dn < 4; ++dn) {
#pragma unroll
    for (int r = 0; r < 4; ++r) {
      const int qA = (qt << 8) + (w << 5) + (g << 2) + r;
      const int d = dn * 16 + lr;
      O[((size_t)(b * 1024 + qA) << 10) + h * 64 + d] = oaccA[dn][r] * rlA[r];
      O[((size_t)(b * 1024 + qA + 16) << 10) + h * 64 + d] =
          oaccB[dn][r] * rlB[r];
    }
  }
}

// ---------------------------------------------------------------------------
extern "C" void kernel_launch(void* const* d_in, const int* in_sizes, int n_in,
                              void* d_out, int out_size, void* d_ws,
                              size_t ws_size, hipStream_t stream) {
  const float* x   = (const float*)d_in[0];
  const float* Wq  = (const float*)d_in[1];
  const float* bq  = (const float*)d_in[2];
  const float* Wk  = (const float*)d_in[3];
  const float* bk  = (const float*)d_in[4];
  const float* Wv  = (const float*)d_in[5];
  const float* bv  = (const float*)d_in[6];
  const float* Wq2 = (const float*)d_in[7];
  const float* bq2 = (const float*)d_in[8];
  const float* Wk2 = (const float*)d_in[9];
  const float* bk2 = (const float*)d_in[10];
  const float* Wv2 = (const float*)d_in[11];
  const float* bv2 = (const float*)d_in[12];

  char* ws = (char*)d_ws;
  short* xbf = (short*)ws;                      // 8 MB
  short* wbf = (short*)(ws + 8388608);          // 12 MB
  short* qkv = (short*)(ws + 20971520);         // 6 x 8 MB

  convert_k<<<2048, 256, 0, stream>>>(x, Wq, Wk, Wv, Wq2, Wk2, Wv2, xbf, wbf);
  proj_t2<<<1024, 256, 0, stream>>>(xbf, wbf, bq, bk, bv, bq2, bk2,
                                    bv2, qkv);
  attn_k<<<512, 512, 0, stream>>>(qkv, (float*)d_out);
}

// Round 21
// 144.455 us; speedup vs baseline: 1.0630x; 1.0630x over previous
//
#include <hip/hip_runtime.h>

// ---------------------------------------------------------------------------
// SelfAttention (dual cross-attention): B=4, S=1024, HID=1024, NH=16, DH=64
//   q1,k1,v1,q2,k2,v2 = x @ W*.T + b*   (bf16 MFMA, f32 accum)
//   out5 = attn(q1,k2,v2), out3 = attn(q2,k1,v1)
// Final configuration (round-19 best: 144.9 us).
// ---------------------------------------------------------------------------

typedef __attribute__((ext_vector_type(8))) short bf16x8;
typedef __attribute__((ext_vector_type(4))) short bf16x4;
typedef __attribute__((ext_vector_type(4))) float f32x4;
typedef __attribute__((ext_vector_type(4))) short s16x4;

#define MFMA16(a, b, c) __builtin_amdgcn_mfma_f32_16x16x32_bf16(a, b, c, 0, 0, 0)
#define BARRIER() asm volatile("s_barrier" ::: "memory")
#define VMCNT0() asm volatile("s_waitcnt vmcnt(0)" ::: "memory")

__device__ __forceinline__ f32x4 mfma16k(bf16x4 a, bf16x4 b, f32x4 c) {
#if __has_builtin(__builtin_amdgcn_mfma_f32_16x16x16bf16_1k)
  return __builtin_amdgcn_mfma_f32_16x16x16bf16_1k(a, b, c, 0, 0, 0);
#elif __has_builtin(__builtin_amdgcn_mfma_f32_16x16x16_bf16)
  return __builtin_amdgcn_mfma_f32_16x16x16_bf16(a, b, c, 0, 0, 0);
#else
  asm volatile("v_mfma_f32_16x16x16_bf16 %0, %1, %2, %0"
               : "+v"(c) : "v"(a), "v"(b));
  return c;
#endif
}

__device__ __forceinline__ unsigned short f2bf(float f) {
  unsigned u = __float_as_uint(f);
  u = (u + 0x7fffu + ((u >> 16) & 1u)) >> 16;  // RNE
  return (unsigned short)u;
}

__device__ __forceinline__ unsigned cvt_pk_bf16(float lo, float hi) {
  unsigned r;
  asm("v_cvt_pk_bf16_f32 %0, %1, %2" : "=v"(r) : "v"(lo), "v"(hi));
  return r;
}

__device__ __forceinline__ void gll16(const void* g, void* l) {
  __builtin_amdgcn_global_load_lds(
      (const __attribute__((address_space(1))) unsigned int*)g,
      (__attribute__((address_space(3))) unsigned int*)l, 16, 0, 0);
}

// ---------------------------------------------------------------------------
// Kernel 1: f32 -> bf16 conversion of x (4M) and the 6 weight matrices
// (6x1M). Grid-stride over 2.62M float4 slots, 2048 blocks (G11).
// ---------------------------------------------------------------------------
__global__ __launch_bounds__(256) void convert_k(
    const float* __restrict__ x,
    const float* __restrict__ W0, const float* __restrict__ W1,
    const float* __restrict__ W2, const float* __restrict__ W3,
    const float* __restrict__ W4, const float* __restrict__ W5,
    short* __restrict__ xbf, short* __restrict__ wbf) {
  const int total = (10 << 20) >> 2;  // 2.62M vec4 slots
  for (int tid = blockIdx.x * 256 + threadIdx.x; tid < total;
       tid += 2048 * 256) {
    const int e = tid << 2;
    const float* src;
    short* dst;
    int off;
    if (e < (4 << 20)) {
      src = x; dst = xbf; off = e;
    } else {
      const int j = e - (4 << 20);
      const int wsel = j >> 20;
      off = j & ((1 << 20) - 1);
      src = (wsel == 0) ? W0 : (wsel == 1) ? W1 : (wsel == 2) ? W2
          : (wsel == 3) ? W3 : (wsel == 4) ? W4 : W5;
      dst = wbf + ((size_t)wsel << 20);
    }
    const float4 v = *(const float4*)(src + off);
    s16x4 o;
    o.x = (short)f2bf(v.x);
    o.y = (short)f2bf(v.y);
    o.z = (short)f2bf(v.z);
    o.w = (short)f2bf(v.w);
    *(s16x4*)(dst + off) = o;
  }
}

// ---------------------------------------------------------------------------
// Kernel 2: projection GEMM. 128x192 block, BK=64, 256 thr (4 waves 2Mx2N,
// wave-tile 64x96), 2 blocks/CU (80 KB LDS), ns-inner L2 mapping (A-panel
// reused x4 back-to-back within XCD), V sub-half swizzle in epilogue.
// ---------------------------------------------------------------------------
__global__ __launch_bounds__(256, 2) void proj_t2(
    const short* __restrict__ Ag, const short* __restrict__ Wall,
    const float* __restrict__ bq, const float* __restrict__ bk,
    const float* __restrict__ bv, const float* __restrict__ bq2,
    const float* __restrict__ bk2, const float* __restrict__ bv2,
    short* __restrict__ qkv) {
  __shared__ __align__(16) short As[2][8192];   // 128 x 64
  __shared__ __align__(16) short Bs[2][12288];  // 192 x 64

  const int bid = blockIdx.x;             // 1024
  const int xcd = bid & 7, i = bid >> 3;  // 128 per XCD
  const int ns = i & 3, mb = i >> 2;      // ns inner: A-panel reused x4
  const int nbase = (xcd * 4 + ns) * 192;
  const int m0 = mb << 7;

  const int t = threadIdx.x, lane = t & 63, w = t >> 6;
  const int g = lane >> 4, lr = lane & 15;
  const int wr = w >> 1, wc = w & 1;      // 2M x 2N waves; wave C = 64x96

  f32x4 acc[4][6] = {};

  auto stage_a = [&](int T) {  // A 128 rows, 4 instr/thread
#pragma unroll
    for (int ld = 0; ld < 4; ++ld) {
      const int slot = (ld << 8) + t;
      const int rr = slot >> 3;
      const int gc = (slot & 7) ^ (rr & 7);
      gll16(Ag + (size_t)(m0 + rr) * 1024 + (T << 6) + (gc << 3),
            &As[T & 1][slot * 8]);
    }
  };
  auto stage_b = [&](int T) {  // B 192 rows, 6 instr/thread
#pragma unroll
    for (int ld = 0; ld < 6; ++ld) {
      const int slot = (ld << 8) + t;
      const int rr = slot >> 3;
      const int gc = (slot & 7) ^ (rr & 7);
      gll16(Wall + (size_t)(nbase + rr) * 1024 + (T << 6) + (gc << 3),
            &Bs[T & 1][slot * 8]);
    }
  };

  stage_a(0); stage_b(0);
  VMCNT0();
  BARRIER();

#define LOAD_A(KK, TB)                                                    \
  _Pragma("unroll") for (int mi = 0; mi < 4; ++mi) {                      \
    const int rA = wr * 64 + mi * 16 + lr;                                \
    af[mi] = *(const bf16x8*)                                             \
        &As[TB][rA * 64 + ((((KK) * 4 + g) ^ (rA & 7)) << 3)];            \
  }
#define LOAD_B(KK, TB)                                                    \
  _Pragma("unroll") for (int nj = 0; nj < 6; ++nj) {                      \
    const int rB = wc * 96 + nj * 16 + lr;                                \
    bf[nj] = *(const bf16x8*)                                             \
        &Bs[TB][rB * 64 + ((((KK) * 4 + g) ^ (rB & 7)) << 3)];            \
  }
#define MFMA_C()                                                          \
  __builtin_amdgcn_s_setprio(1);                                          \
  _Pragma("unroll") for (int mi = 0; mi < 4; ++mi)                        \
    _Pragma("unroll") for (int nj = 0; nj < 6; ++nj)                      \
      acc[mi][nj] = MFMA16(af[mi], bf[nj], acc[mi][nj]);                  \
  __builtin_amdgcn_s_setprio(0);

  for (int T = 0; T < 16; ++T) {
    const int C = T & 1;
    const bool DV = T < 15;
    bf16x8 af[4], bf[6];
    { // phase 1: kk0 (10 ds); dribble next tile's A (4 gll16)
      LOAD_A(0, C); LOAD_B(0, C);
      if (DV) stage_a(T + 1);
      BARRIER();
      MFMA_C();
      BARRIER();
    }
    { // phase 2: kk1 (10 ds); dribble next tile's B (6 gll16); certify
      LOAD_A(1, C); LOAD_B(1, C);
      if (DV) stage_b(T + 1);
      BARRIER();
      MFMA_C();
      VMCNT0();
      BARRIER();
    }
  }

#undef LOAD_A
#undef LOAD_B
#undef MFMA_C

  // ---- epilogue: bias + bf16 pack into attention layouts (per-column p) ----
#pragma unroll
  for (int nj = 0; nj < 6; ++nj) {
    const int nn = nbase + wc * 96 + nj * 16 + lr;
    const int p = nn >> 10, nl = nn & 1023;
    const float* bp = (p == 0) ? bq : (p == 1) ? bk : (p == 2) ? bv
                    : (p == 3) ? bq2 : (p == 4) ? bk2 : bv2;
    const float bb = bp[nl];
    const int h = nl >> 6, d = nl & 63;
    const int pt = (p == 0 || p == 3) ? 0 : (p == 1 || p == 4) ? 1 : 2;
    unsigned short* dst = (unsigned short*)qkv + ((size_t)p << 22);
#pragma unroll
    for (int mi = 0; mi < 4; ++mi) {
#pragma unroll
      for (int r = 0; r < 4; ++r) {
        const int m = m0 + wr * 64 + mi * 16 + (g << 2) + r;
        const int b = m >> 10, s = m & 1023;
        const unsigned short val = f2bf(acc[mi][nj][r] + bb);
        size_t idx;
        if (pt == 0) {
          idx = ((size_t)(((b << 4) + h) * 1024 + s) << 6) + d;
        } else if (pt == 1) {
          const int d2 = (d & 7) | (((d >> 3) ^ (s & 7)) << 3);
          idx = ((size_t)(((b << 4) + h) * 1024 + s) << 6) + d2;
        } else {
          const int tt = s >> 6, s2 = s & 63;
          const int w2 = (s2 & 7) ^ (((d >> 3) & 1) << 2);
          const int s3 = w2 | (((s2 >> 3) ^ (d & 7)) << 3);
          idx = ((size_t)((((b << 4) + h) * 16 + tt) * 64 + d) << 6) + s3;
        }
        dst[idx] = val;
      }
    }
  }
}

// ---------------------------------------------------------------------------
// Kernel 3: flash attention, swapped-QK^T in-register-P form; 128-row Q-tile
// (8 waves, 512 thr), double-buffered KV (32 KB -> 4 blocks/CU), KV loop
// unrolled x2 with literal buffer indices, V-read sub-half swizzle
// (conflict-free 8B reads). Round-19 version.
// ---------------------------------------------------------------------------
__global__ __launch_bounds__(512) void attn_k(const short* __restrict__ qkv,
                                              float* __restrict__ out) {
  __shared__ __align__(16) short Ks[2][64 * 64];
  __shared__ __align__(16) short Vs[2][64 * 64];

  const int L = blockIdx.x;  // 1024 blocks
  const int xcd = L & 7, ss = L >> 3;   // ss 0..127
  const int qt = ss & 7, pg = ss >> 3;  // 8 q-tiles of 128 rows
  const int pp = xcd + (pg << 3);  // all q-tiles of a head share an XCD
  const int hb = pp & 63, dir = pp >> 6;

  const short* Q = qkv + ((size_t)(dir ? 3 : 0) << 22) + ((size_t)hb << 16);
  const short* K = qkv + ((size_t)(dir ? 1 : 4) << 22) + ((size_t)hb << 16);
  const short* V = qkv + ((size_t)(dir ? 2 : 5) << 22) + ((size_t)hb << 16);
  float* O = out + ((size_t)dir << 22);

  const int t = threadIdx.x, lane = t & 63, w = t >> 6;  // w 0..7
  const int g = lane >> 4, lr = lane & 15;

  const int qrow = (qt << 7) + (w << 4) + lr;
  bf16x8 qf[2];
  qf[0] = *(const bf16x8*)(Q + qrow * 64 + g * 8);
  qf[1] = *(const bf16x8*)(Q + qrow * 64 + 32 + g * 8);

  const bf16x4 ones4 = {0x3F80, 0x3F80, 0x3F80, 0x3F80};

  f32x4 oacc[4] = {};
  f32x4 lacc = {};
  float mrun = -3.0e38f;               // running max for q = lr (log2 units)
  const float CSC = 0.18033688f;       // (1/8) * log2(e)

  const int srow = t >> 3;             // staging row 0..63 (1 gll16/thread)
  const int scol = (t & 7) << 3;

  auto stage = [&](int kt, int buf) {
    gll16(K + (size_t)((kt << 6) + srow) * 64 + scol, &Ks[buf][w << 9]);
    gll16(V + (size_t)(kt << 12) + (size_t)srow * 64 + scol, &Vs[buf][w << 9]);
  };

  // one KV tile with compile-time buffer index CUR
  auto tile = [&](int kt, auto curc) {
    constexpr int CUR = decltype(curc)::value;
    if (kt < 15) stage(kt + 1, CUR ^ 1);

    // ---- S^T = K Q^T (swapped): lane gets P^T[k=kn*16+g*4+r][q=lr] ----
    f32x4 sc2[4] = {};
    __builtin_amdgcn_s_setprio(1);
#pragma unroll
    for (int dk = 0; dk < 2; ++dk) {
#pragma unroll
      for (int kn = 0; kn < 4; ++kn) {
        const int krow = kn * 16 + lr;
        const bf16x8 kf = *(const bf16x8*)
            &Ks[CUR][krow * 64 +
                     ((((dk << 6) + (g << 4)) ^ ((krow & 7) << 4)) >> 1)];
        sc2[kn] = MFMA16(kf, qf[dk], sc2[kn]);
      }
    }
    __builtin_amdgcn_s_setprio(0);

    // ---- softmax (per-lane scalar state, defer-max) ----
    float tm = fmaxf(fmaxf(fmaxf(sc2[0][0], sc2[0][1]),
                           fmaxf(sc2[0][2], sc2[0][3])),
                     fmaxf(fmaxf(sc2[1][0], sc2[1][1]),
                           fmaxf(sc2[1][2], sc2[1][3])));
    tm = fmaxf(tm, fmaxf(fmaxf(fmaxf(sc2[2][0], sc2[2][1]),
                               fmaxf(sc2[2][2], sc2[2][3])),
                         fmaxf(fmaxf(sc2[3][0], sc2[3][1]),
                               fmaxf(sc2[3][2], sc2[3][3]))));
    const bool ok = __all(fmaf(tm, CSC, -mrun) <= 8.0f);
    if (!ok) {
      float t2 = fmaxf(tm, __shfl_xor(tm, 16));
      t2 = fmaxf(t2, __shfl_xor(t2, 32));
      const float mnew = fmaxf(mrun, t2 * CSC);
      const float scq = exp2f(mrun - mnew);  // scale for q = lr
      mrun = mnew;
#pragma unroll
      for (int r = 0; r < 4; ++r) {
        const float sr = __shfl(scq, (g << 2) + r);  // scale for q = g*4+r
        lacc[r] *= sr;
#pragma unroll
        for (int dn = 0; dn < 4; ++dn) oacc[dn][r] *= sr;
      }
    }

    bf16x4 pa[4];
#pragma unroll
    for (int kn = 0; kn < 4; ++kn) {
      const float p0 = exp2f(fmaf(sc2[kn][0], CSC, -mrun));
      const float p1 = exp2f(fmaf(sc2[kn][1], CSC, -mrun));
      const float p2 = exp2f(fmaf(sc2[kn][2], CSC, -mrun));
      const float p3 = exp2f(fmaf(sc2[kn][3], CSC, -mrun));
      union { unsigned u[2]; bf16x4 v; } pk;
      pk.u[0] = cvt_pk_bf16(p0, p1);
      pk.u[1] = cvt_pk_bf16(p2, p3);
      pa[kn] = pk.v;
    }

    // ---- O += P V ; l += P @ ones  (K=16 MFMAs, P straight from regs) ----
    __builtin_amdgcn_s_setprio(1);
#pragma unroll
    for (int kn = 0; kn < 4; ++kn) {
      lacc = mfma16k(pa[kn], ones4, lacc);
#pragma unroll
      for (int dn = 0; dn < 4; ++dn) {
        const int vrow = dn * 16 + lr;
        const int ch = (2 * kn + (g >> 1)) ^ (vrow & 7);  // 16B-chunk swizzle
        const int sub = (((g & 1) ^ ((lr >> 3) & 1)) << 2);  // 8B sub-half
        const bf16x4 vf = *(const bf16x4*)
            &Vs[CUR][vrow * 64 + ch * 8 + sub];
        oacc[dn] = mfma16k(pa[kn], vf, oacc[dn]);
      }
    }
    __builtin_amdgcn_s_setprio(0);

    VMCNT0();
    BARRIER();
  };

  stage(0, 0);
  VMCNT0();
  BARRIER();

#pragma unroll
  for (int kp = 0; kp < 8; ++kp) {
    tile(2 * kp, std::integral_constant<int, 0>{});
    tile(2 * kp + 1, std::integral_constant<int, 1>{});
  }

  // ---- epilogue: out[b][q][h*64+d] = oacc / l ----
  const int b = hb >> 4, h = hb & 15;
  float rl[4];
#pragma unroll
  for (int r = 0; r < 4; ++r) rl[r] = 1.0f / lacc[r];
#pragma unroll
  for (int dn = 0; dn < 4; ++dn) {
#pragma unroll
    for (int r = 0; r < 4; ++r) {
      const int q = (qt << 7) + (w << 4) + (g << 2) + r;
      const int d = dn * 16 + lr;
      O[((size_t)(b * 1024 + q) << 10) + h * 64 + d] = oacc[dn][r] * rl[r];
    }
  }
}

// ---------------------------------------------------------------------------
extern "C" void kernel_launch(void* const* d_in, const int* in_sizes, int n_in,
                              void* d_out, int out_size, void* d_ws,
                              size_t ws_size, hipStream_t stream) {
  const float* x   = (const float*)d_in[0];
  const float* Wq  = (const float*)d_in[1];
  const float* bq  = (const float*)d_in[2];
  const float* Wk  = (const float*)d_in[3];
  const float* bk  = (const float*)d_in[4];
  const float* Wv  = (const float*)d_in[5];
  const float* bv  = (const float*)d_in[6];
  const float* Wq2 = (const float*)d_in[7];
  const float* bq2 = (const float*)d_in[8];
  const float* Wk2 = (const float*)d_in[9];
  const float* bk2 = (const float*)d_in[10];
  const float* Wv2 = (const float*)d_in[11];
  const float* bv2 = (const float*)d_in[12];

  char* ws = (char*)d_ws;
  short* xbf = (short*)ws;                      // 8 MB
  short* wbf = (short*)(ws + 8388608);          // 12 MB
  short* qkv = (short*)(ws + 20971520);         // 6 x 8 MB

  convert_k<<<2048, 256, 0, stream>>>(x, Wq, Wk, Wv, Wq2, Wk2, Wv2, xbf, wbf);
  proj_t2<<<1024, 256, 0, stream>>>(xbf, wbf, bq, bk, bv, bq2, bk2,
                                    bv2, qkv);
  attn_k<<<1024, 512, 0, stream>>>(qkv, (float*)d_out);
}